// Round 17
// baseline (626.676 us; speedup 1.0000x reference)
//
#include <hip/hip_runtime.h>
#include <hip/hip_bf16.h>
#include <stdint.h>

#define N_NODES 100000
#define N_EDGES 1600000
#define N_RELS  19
#define NQ      4                   // dst quarters
#define QN      25000               // nodes per quarter
#define QTILES  196                 // ceil(QN/128)
#define NBQ     98                  // scan blocks per quarter (256 nodes each)
#define NSB     (NQ * NBQ)          // 392
#define N_BUCK  (NQ * N_RELS)       // 76
#define NBIN    391                 // dst bins of 256 nodes
#define NGR     8                   // counter groups (~XCDs); blk%8 -> same XCD
#define NBK8    (N_BUCK * NGR)      // 608
#define NBIN8   (NBIN * NGR)       // 3128
#define NHC     (N_BUCK + NBIN)     // 467 hist counters per block
#define NHC2    (2 * NHC)           // 934: [hK|hB|lK|lB]
#define MSGQ    460000              // msg rows per quarter (edges + QN + margin)
#define NCKQ    3700                // gemm grid per quarter pass
#define NCK_TOT 14000
#define EPB     2048                // edges per S1 block
#define S1B     782                 // ceil(N_EDGES/EPB)

typedef __attribute__((ext_vector_type(8))) short bf16x8;
typedef __attribute__((ext_vector_type(4))) float f32x4;
typedef __attribute__((ext_vector_type(4))) int   int4v;

__device__ __forceinline__ unsigned short f2bf(float x) {
  union { float f; unsigned u; } v; v.f = x;
  unsigned r = v.u + 0x7FFF + ((v.u >> 16) & 1);
  return (unsigned short)(r >> 16);
}
__device__ __forceinline__ float bf2f(unsigned short b) {
  union { unsigned u; float f; } v; v.u = ((unsigned)b) << 16; return v.f;
}
// bijective XCD swizzle (m204): blockIdx b (round-robin over 8 XCDs) ->
// logical id so each XCD gets a CONTIGUOUS chunk range (L2 locality).
__device__ __forceinline__ int xcd_swz(int b, int nwg) {
  int q = nwg >> 3, r = nwg & 7;
  int x = b & 7, i = b >> 3;
  int base = (x < r) ? x * (q + 1) : r * (q + 1) + (x - r) * q;
  return base + i;
}

// ---------------- weight prep: transpose + bf16 convert ----------------
__global__ void k_prep_w(const float* W1, const float* W2,
                         const float* Wl1, const float* Wl2,
                         unsigned short* Wt1, unsigned short* Wt2,
                         unsigned short* Wtl1, unsigned short* Wtl2) {
  int i = blockIdx.x * 256 + threadIdx.x;
  const int s1 = N_RELS * 128 * 128;
  const int s2 = N_RELS * 64 * 128;
  const int s3 = 128 * 128;
  const int s4 = 64 * 128;
  if (i < s1) {
    int r = i / (128 * 128); int rem = i % (128 * 128);
    int n = rem / 128, k = rem % 128;
    Wt1[i] = f2bf(W1[((size_t)r * 128 + k) * 128 + n]);
  } else if (i < s1 + s2) {
    int j = i - s1;
    int r = j / (64 * 128); int rem = j % (64 * 128);
    int n = rem / 128, k = rem % 128;
    Wt2[j] = f2bf(W2[((size_t)r * 128 + k) * 64 + n]);
  } else if (i < s1 + s2 + s3) {
    int j = i - s1 - s2; int n = j / 128, k = j % 128;
    Wtl1[j] = f2bf(Wl1[k * 128 + n]);
  } else if (i < s1 + s2 + s3 + s4) {
    int j = i - s1 - s2 - s3; int n = j / 128, k = j % 128;
    Wtl2[j] = f2bf(Wl2[k * 64 + n]);
  }
}

// ---- histogram + local exclusive scans; persists [hK|hB|lK|lB] ----
// 512 threads: halves histogram atomic chains; scans guarded to t<256
__launch_bounds__(512)
__global__ void k_hist(const int* __restrict__ dst, const int* __restrict__ et,
                       int* __restrict__ bcount8, int* __restrict__ bincount8,
                       int* __restrict__ histAll) {
  __shared__ int hK[N_BUCK], hB[NBIN];
  __shared__ int sb[256];
  int t = threadIdx.x, g = blockIdx.x & (NGR - 1);
  for (int i = t; i < N_BUCK; i += 512) hK[i] = 0;
  for (int i = t; i < NBIN; i += 512) hB[i] = 0;
  __syncthreads();
  int e0 = blockIdx.x * EPB;
  for (int r = 0; r < EPB / 512; r++) {
    int e = e0 + r * 512 + t;
    if (e < N_EDGES) {
      int d = dst[e];
      atomicAdd(&hK[(d / QN) * N_RELS + et[e]], 1);
      atomicAdd(&hB[d >> 8], 1);
    }
  }
  __syncthreads();
  int* hout = histAll + (size_t)blockIdx.x * NHC2;
  for (int i = t; i < N_BUCK; i += 512) {
    hout[i] = hK[i];
    if (hK[i]) atomicAdd(&bcount8[i * NGR + g], hK[i]);
  }
  for (int i = t; i < NBIN; i += 512) {
    hout[N_BUCK + i] = hB[i];
    if (hB[i]) atomicAdd(&bincount8[i * NGR + g], hB[i]);
  }
  // local exclusive scan hK -> lK  (threads 0..255)
  {
    int v0 = 0, v1 = 0;
    if (t < 256) {
      v0 = (2 * t < N_BUCK) ? hK[2 * t] : 0;
      v1 = (2 * t + 1 < N_BUCK) ? hK[2 * t + 1] : 0;
      sb[t] = v0 + v1;
    }
    __syncthreads();
    for (int s = 1; s < 256; s <<= 1) {
      int x = 0;
      if (t < 256 && t >= s) x = sb[t - s];
      __syncthreads();
      if (t < 256) sb[t] += x;
      __syncthreads();
    }
    if (t < 256) {
      int base = sb[t] - v0 - v1;
      if (2 * t < N_BUCK) hout[NHC + 2 * t] = base;
      if (2 * t + 1 < N_BUCK) hout[NHC + 2 * t + 1] = base + v0;
    }
    __syncthreads();
  }
  // local exclusive scan hB -> lB  (threads 0..255)
  {
    int v0 = 0, v1 = 0;
    if (t < 256) {
      v0 = (2 * t < NBIN) ? hB[2 * t] : 0;
      v1 = (2 * t + 1 < NBIN) ? hB[2 * t + 1] : 0;
      sb[t] = v0 + v1;
    }
    __syncthreads();
    for (int s = 1; s < 256; s <<= 1) {
      int x = 0;
      if (t < 256 && t >= s) x = sb[t - s];
      __syncthreads();
      if (t < 256) sb[t] += x;
      __syncthreads();
    }
    if (t < 256) {
      int base = sb[t] - v0 - v1;
      if (2 * t < NBIN) hout[NHC + N_BUCK + 2 * t] = base;
      if (2 * t + 1 < NBIN) hout[NHC + N_BUCK + 2 * t + 1] = base + v0;
    }
  }
}

// ---- scan0: bucket/chunk bases + (bucket,group)/(bin,group) prefix ----
__global__ void k_scan0(const int* __restrict__ bcount8, const int* __restrict__ bincount8,
                        int* boff, int* bcur8, int* cbase, int* qcs, int* selfb,
                        int* binoff8, int* bincur8) {
  __shared__ int shK[NBK8];
  __shared__ int sb76[N_BUCK];
  __shared__ int sbs[N_BUCK];
  __shared__ int sh[512];
  int t = threadIdx.x;   // 512
  for (int i = t; i < NBK8; i += 512) shK[i] = bcount8[i];
  __syncthreads();
  if (t < N_BUCK) {
    int s = 0;
    for (int gg = 0; gg < NGR; gg++) s += shK[t * NGR + gg];
    sb76[t] = s;
  }
  __syncthreads();
  if (t == 0) {
    int a = 0, cb = 0;
    for (int q = 0; q < NQ; q++) {
      qcs[q] = cb;
      for (int r = 0; r < N_RELS; r++) {
        int b = q * N_RELS + r;
        boff[b] = a; sbs[b] = a; cbase[b] = cb;
        a += sb76[b]; cb += (sb76[b] + 127) >> 7;
      }
      selfb[q] = cb; cb += QTILES;
    }
    qcs[NQ] = cb;
    boff[N_BUCK] = a;
  }
  __syncthreads();
  for (int i = t; i < NBK8; i += 512) {
    int b = i >> 3, gg = i & (NGR - 1);
    int base = sbs[b];
    for (int k = 0; k < gg; k++) base += shK[b * NGR + k];
    bcur8[i] = base;
  }
  // ---- bin part: exclusive scan of 3128 per-(bin,group) counts ----
  int vals[7];
  int i0 = t * 7;
  int loc = 0;
  for (int k = 0; k < 7; k++) {
    int i = i0 + k;
    int v = (i < NBIN8) ? bincount8[i] : 0;
    vals[k] = v; loc += v;
  }
  sh[t] = loc;
  __syncthreads();
  for (int s = 1; s < 512; s <<= 1) {
    int x = (t >= s) ? sh[t - s] : 0;
    __syncthreads();
    sh[t] += x;
    __syncthreads();
  }
  int run = sh[t] - loc;
  for (int k = 0; k < 7; k++) {
    int i = i0 + k;
    if (i < NBIN8) { binoff8[i] = run; bincur8[i] = run; run += vals[k]; }
  }
  if (t == 511) binoff8[NBIN8] = sh[511];   // total
}

// ---- S1a: bucket counting-sort -> srcS (coalesced runs) + posE (seq) ----
__launch_bounds__(512)
__global__ void k_scat1a(const int* __restrict__ src, const int* __restrict__ dst,
                         const int* __restrict__ et,
                         const int* __restrict__ histAll,
                         int* __restrict__ bcur8,
                         int* __restrict__ srcS, int* __restrict__ posE) {
  __shared__ int sortK[EPB];
  __shared__ int lK[N_BUCK], gKr[N_BUCK];
  int t = threadIdx.x, blk = blockIdx.x, g = blk & (NGR - 1);
  const int* hin = histAll + (size_t)blk * NHC2;
  for (int i = t; i < N_BUCK; i += 512) {
    int h = hin[i], l = hin[NHC + i];
    lK[i] = l;
    gKr[i] = h ? (atomicAdd(&bcur8[i * NGR + g], h) - l) : 0;
  }
  __syncthreads();
  int e0 = blk * EPB;
  int nval = min(EPB, N_EDGES - e0);
  for (int r = 0; r < EPB / 512; r++) {
    int e = e0 + r * 512 + t;
    if (e < N_EDGES) {
      int d = dst[e], rl = et[e], sv = src[e];
      int bk = (d / QN) * N_RELS + rl;
      int lrk = atomicAdd(&lK[bk], 1);
      sortK[lrk] = sv | (bk << 17);
      posE[e] = gKr[bk] + lrk;      // global bucket position, seq write in e
    }
  }
  __syncthreads();
  for (int r = 0; r < EPB / 512; r++) {
    int s = r * 512 + t;
    if (s < nval) {
      int v = sortK[s];
      srcS[gKr[v >> 17] + s] = v & 0x1FFFF;
    }
  }
}

// ---- S1b: bin counting-sort -> stgA/stgB (coalesced runs), 512 threads ----
__launch_bounds__(512)
__global__ void k_scat1b(const int* __restrict__ src, const int* __restrict__ dst,
                         const int* __restrict__ et,
                         const int* __restrict__ posE,
                         const int* __restrict__ histAll,
                         int* __restrict__ bincur8,
                         int* __restrict__ stgA, int* __restrict__ stgB) {
  __shared__ int sortA[EPB], sortBv[EPB];
  __shared__ int lB[NBIN], gBr[NBIN];
  int t = threadIdx.x, blk = blockIdx.x, g = blk & (NGR - 1);
  const int* hin = histAll + (size_t)blk * NHC2;
  for (int i = t; i < NBIN; i += 512) {
    int h = hin[N_BUCK + i], l = hin[NHC + N_BUCK + i];
    lB[i] = l;
    gBr[i] = h ? (atomicAdd(&bincur8[i * NGR + g], h) - l) : 0;
  }
  __syncthreads();
  int e0 = blk * EPB;
  int nval = min(EPB, N_EDGES - e0);
  for (int r = 0; r < EPB / 512; r++) {
    int e = e0 + r * 512 + t;
    if (e < N_EDGES) {
      int d = dst[e], rl = et[e], sv = src[e];
      int gpos = posE[e];
      int bn = d >> 8;
      int lrb = atomicAdd(&lB[bn], 1);
      sortA[lrb] = gpos | (rl << 21) | ((bn & 63) << 26);
      sortBv[lrb] = sv | ((d & 255) << 17) | ((bn >> 6) << 25);
    }
  }
  __syncthreads();
  for (int r = 0; r < EPB / 512; r++) {
    int s = r * 512 + t;
    if (s < nval) {
      int a = sortA[s], b = sortBv[s];
      int bn = ((a >> 26) & 63) | (((b >> 25) & 7) << 6);
      int adr = gBr[bn] + s;
      stgA[adr] = a & 0x03FFFFFF;
      stgB[adr] = b & 0x01FFFFFF;
    }
  }
}

// ---- S2a: per-bin indegree counts (single-writer, no global atomics) ----
__global__ void k_cnt(const int* __restrict__ stgB, const int* __restrict__ binoff8,
                      int* __restrict__ ncount) {
  __shared__ int c[256];
  int b = blockIdx.x, t = threadIdx.x;
  c[t] = 0;
  __syncthreads();
  int lo = binoff8[b * NGR], hi = binoff8[b * NGR + NGR];
  for (int s = lo + t; s < hi; s += 256)
    atomicAdd(&c[(stgB[s] >> 17) & 255], 1);
  __syncthreads();
  int n = b * 256 + t;
  if (n < N_NODES) ncount[n] = c[t];
}

// ---- scan stage A: per-256-node block sums of (ncount+1) ----
__global__ void k_scanA(const int* __restrict__ ncount, int* __restrict__ bsum) {
  __shared__ int sh[256];
  int b = blockIdx.x, t = threadIdx.x;
  int q = b / NBQ, bb = b % NBQ;
  int i = bb * 256 + t;
  int val = (i < QN) ? (ncount[q * QN + i] + 1) : 0;
  sh[t] = val;
  __syncthreads();
  for (int s = 128; s > 0; s >>= 1) {
    if (t < s) sh[t] += sh[t + s];
    __syncthreads();
  }
  if (t == 0) bsum[b] = sh[0];
}

// ---- scan stage B: per-quarter prefix over block sums + sentinels ----
__global__ void k_scanB(const int* bsum, int* bbase, int* nodeoff) {
  __shared__ int sh[NSB];
  int t = threadIdx.x;   // 512
  if (t < NSB) sh[t] = bsum[t];
  __syncthreads();
  if (t < NQ) {
    int a = 0;
    for (int i = 0; i < NBQ; i++) {
      int v = sh[t * NBQ + i]; sh[t * NBQ + i] = a; a += v;
    }
    nodeoff[(t + 1) * QN + t] = a;      // quarter sentinel
  }
  __syncthreads();
  if (t < NSB) bbase[t] = sh[t];
}

// ---- scan stage C: intra-block scan -> nodeoff; also gfwd self slots ----
__global__ void k_scanC(const int* __restrict__ ncount,
                        const int* __restrict__ bbase,
                        const int* __restrict__ boff,
                        int* __restrict__ nodeoff, int* __restrict__ gfwd) {
  __shared__ int sh[256];
  int b = blockIdx.x, t = threadIdx.x;
  int q = b / NBQ, bb = b % NBQ;
  int i = bb * 256 + t;
  int val = (i < QN) ? (ncount[q * QN + i] + 1) : 0;
  sh[t] = val;
  __syncthreads();
  for (int s = 1; s < 256; s <<= 1) {
    int x = (t >= s) ? sh[t - s] : 0;
    __syncthreads();
    sh[t] += x;
    __syncthreads();
  }
  int excl = sh[t] - val + bbase[b];
  if (i < QN) {
    int n = q * QN + i;
    nodeoff[n + q] = excl;                 // slot 0 of run = self message
    int qedges = boff[(q + 1) * N_RELS] - boff[q * N_RELS];
    gfwd[(size_t)q * MSGQ + qedges + i] = excl;   // self pos -> slot
  }
}

// ---- S2b: slot assignment -> gfwd[pos]=slot + fused R accumulation ----
__launch_bounds__(512)
__global__ void k_scat2(const int* __restrict__ stgA, const int* __restrict__ stgB,
                        const int* __restrict__ binoff8,
                        const int* __restrict__ nodeoff,
                        const int* __restrict__ boff,
                        const int* __restrict__ ncount,
                        int* __restrict__ gfwd, int* __restrict__ Rg) {
  __shared__ int cur[256];
  __shared__ int R[256][N_RELS];
  __shared__ int qe0s[NQ + 1];
  int b = blockIdx.x, t = threadIdx.x;
  if (t <= NQ) qe0s[t] = boff[t * N_RELS];
  if (t < 256) {
    int n = b * 256 + t;
    if (n < N_NODES) {
      int q = n / QN;
      cur[t] = nodeoff[n + q] + 1;
    }
#pragma unroll
    for (int r = 0; r < N_RELS; r++) R[t][r] = 0;
  }
  __syncthreads();
  int lo = binoff8[b * NGR], hi = binoff8[b * NGR + NGR];
  for (int s = lo + t; s < hi; s += 512) {
    int a = stgA[s], bb = stgB[s];
    int dlow = (bb >> 17) & 255;
    int slot = atomicAdd(&cur[dlow], 1);
    int pos = a & 0x1FFFFF, rel = (a >> 21) & 31;
    int sv = bb & 0x1FFFF;
    int d = b * 256 + dlow;
    int q = d / QN;
    gfwd[(size_t)q * MSGQ + (pos - qe0s[q])] = slot;
    atomicAdd(&R[dlow][rel], ncount[sv]);
  }
  __syncthreads();
  if (t < 256) {
    int n = b * 256 + t;
    if (n < N_NODES) {
#pragma unroll
      for (int r = 0; r < N_RELS; r++)
        Rg[(size_t)r * N_NODES + n] = R[t][r];
    }
  }
}

// ---- layer 0 dense: h1 = relu([R|deg]·W0ext + b0), LDS-staged linear write ----
__launch_bounds__(256, 3)
__global__ void k_h1(const int* __restrict__ Rg, const int* __restrict__ ncount,
                     const float* __restrict__ W0, const float* __restrict__ Wl0,
                     const float* __restrict__ b0,
                     unsigned short* __restrict__ h1) {
  __shared__ float W0s[N_RELS * 128];
  __shared__ float wl[128], bb[128];
  __shared__ __align__(16) unsigned short Hs[128 * 128];
  int t = threadIdx.x, blk = blockIdx.x;
  for (int i = t; i < N_RELS * 128; i += 256) W0s[i] = W0[i];
  if (t < 128) { wl[t] = Wl0[t]; bb[t] = b0[t]; }
  __syncthreads();
  int n0 = blk * 128;
  int cnt = min(128, N_NODES - n0);
  int ln = t >> 1;                 // local node (2 threads per node)
  int half = (t & 1) * 64;         // this thread's 64-col half
  if (ln < cnt) {
    int n = n0 + ln;
    float rr[N_RELS];
#pragma unroll
    for (int r = 0; r < N_RELS; r++) rr[r] = (float)Rg[(size_t)r * N_NODES + n];
    float dn = (float)ncount[n];
    for (int c0 = half; c0 < half + 64; c0 += 8) {
      float acc[8];
#pragma unroll
      for (int j = 0; j < 8; j++) acc[j] = dn * wl[c0 + j] + bb[c0 + j];
      for (int r = 0; r < N_RELS; r++) {
#pragma unroll
        for (int j = 0; j < 8; j++)
          acc[j] += rr[r] * W0s[r * 128 + c0 + j];
      }
      unsigned vs[4];
#pragma unroll
      for (int j = 0; j < 4; j++) {
        float x0 = fmaxf(acc[2 * j], 0.f), x1 = fmaxf(acc[2 * j + 1], 0.f);
        vs[j] = (unsigned)f2bf(x0) | ((unsigned)f2bf(x1) << 16);
      }
      int4v o = {(int)vs[0], (int)vs[1], (int)vs[2], (int)vs[3]};
      *(int4v*)&Hs[ln * 128 + c0] = o;
    }
  }
  __syncthreads();
  int tot = cnt * 16;              // 16 x 16B chunks per node row
  for (int task = t; task < tot; task += 256)
    *(int4v*)&h1[(size_t)n0 * 128 + task * 8] = *(const int4v*)&Hs[task * 8];
}

// ---- chunk list: edge chunks per bucket + self chunks per quarter ----
__global__ void k_fill(const int* boff, const int* cbase,
                       const int* selfb, int* cA, int* cB) {
  int b = blockIdx.x;
  if (b < N_BUCK) {
    int cnt = boff[b + 1] - boff[b], e0 = boff[b], w0 = cbase[b];
    int rel = b % N_RELS;
    int nch = (cnt + 127) >> 7;
    for (int i = threadIdx.x; i < nch; i += blockDim.x) {
      cA[w0 + i] = (e0 + i * 128) | (rel << 21);
      cB[w0 + i] = min(128, cnt - i * 128);
    }
  } else {
    int q = b - N_BUCK;
    int w0 = selfb[q];
    for (int i = threadIdx.x; i < QTILES; i += blockDim.x) {
      cA[w0 + i] = (i * 128) | (19 << 21);
      cB[w0 + i] = min(128, QN - i * 128);
    }
  }
}

// ---- phase 1: GEMM -> msg rows scattered to DST-SORTED slots via gfwd ----
// nqp quarters per launch; XCD-bijective grid swizzle for L2 locality
template <int NOUT>
__launch_bounds__(256, NOUT == 64 ? 6 : 4)
__global__ void k_gemm_msg(const unsigned short* __restrict__ hprev,  // bf16 N x 128
                           const unsigned short* __restrict__ Wt,    // [19][NOUT][128]
                           const unsigned short* __restrict__ Wtl,   // [NOUT][128]
                           const int* __restrict__ qcs, int q0, int nqp,
                           const int* __restrict__ cA,
                           const int* __restrict__ cB,
                           const int* __restrict__ srcS,
                           const int* __restrict__ boff,
                           const int* __restrict__ gfwd,   // full (quarter-major)
                           unsigned short* __restrict__ msg) {
  const int LDK = 136;                    // B stride (shorts)
  const int CLD = NOUT + 8;               // C stride (shorts)
  const int SH = (NOUT * LDK > 128 * CLD) ? NOUT * LDK : 128 * CLD;
  __shared__ __align__(16) unsigned short Bs[SH];

  int cs = qcs[q0], ce = qcs[q0 + nqp];
  int w = xcd_swz(blockIdx.x, gridDim.x);
  if (w >= ce - cs) return;
  w += cs;
  int qq = q0;
  if (nqp == 2 && w >= qcs[q0 + 1]) qq = q0 + 1;
  int pa = cA[w];
  int e0 = pa & 0x1FFFFF, rel = pa >> 21;
  int cnt = cB[w];
  bool self = (rel == 19);
  const unsigned short* wsrc = self ? Wtl : (Wt + (size_t)rel * NOUT * 128);
  int qe0 = boff[qq * N_RELS];
  int qedges = boff[(qq + 1) * N_RELS] - qe0;
  int ppos0 = self ? (qedges + e0) : (e0 - qe0);
  const int* gf = gfwd + (size_t)qq * MSGQ;
  unsigned short* msgq = msg + (size_t)(qq - q0) * MSGQ * NOUT;
  int tid = threadIdx.x;
  const int lane = tid & 63, wid = tid >> 6;

  int rowg[2]; bool valv[2];
#pragma unroll
  for (int fi = 0; fi < 2; fi++) {
    int m = wid * 32 + fi * 16 + (lane & 15);
    bool v = m < cnt;
    valv[fi] = v;
    int row = 0;
    if (v) row = self ? (qq * QN + e0 + m) : srcS[e0 + m];
    rowg[fi] = row;
  }
  bf16x8 a[2][4];
#pragma unroll
  for (int fi = 0; fi < 2; fi++) {
    const unsigned short* rp = hprev + (size_t)rowg[fi] * 128 + (lane >> 4) * 8;
#pragma unroll
    for (int kk = 0; kk < 4; kk++)
      a[fi][kk] = *(const bf16x8*)&rp[kk * 32];
  }
#pragma unroll
  for (int fi = 0; fi < 2; fi++)
    if (!valv[fi]) {
#pragma unroll
      for (int kk = 0; kk < 4; kk++)
        a[fi][kk] = (bf16x8){0, 0, 0, 0, 0, 0, 0, 0};
    }

  for (int task = tid; task < NOUT * 16; task += 256) {
    int n = task >> 4, c = task & 15;
    *(int4v*)&Bs[n * LDK + c * 8] = *(const int4v*)&wsrc[n * 128 + c * 8];
  }
  __syncthreads();

  const int FJ = NOUT / 16;
  f32x4 acc[2][FJ];
#pragma unroll
  for (int i = 0; i < 2; i++)
#pragma unroll
    for (int j = 0; j < FJ; j++) acc[i][j] = (f32x4){0.f, 0.f, 0.f, 0.f};

#pragma unroll
  for (int kk = 0; kk < 4; kk++) {
    int kof = kk * 32 + (lane >> 4) * 8;
    bf16x8 b[FJ];
#pragma unroll
    for (int fj = 0; fj < FJ; fj++)
      b[fj] = *(const bf16x8*)&Bs[(fj * 16 + (lane & 15)) * LDK + kof];
#pragma unroll
    for (int fi = 0; fi < 2; fi++)
#pragma unroll
      for (int fj = 0; fj < FJ; fj++)
        acc[fi][fj] = __builtin_amdgcn_mfma_f32_16x16x32_bf16(a[fi][kk], b[fj], acc[fi][fj], 0, 0, 0);
  }

  // ---- epilogue: C -> LDS (stride CLD) -> scattered full-row 16B stores ----
  __syncthreads();                       // all waves done reading Bs
  // C/D: col=lane&15, row=(lane>>4)*4+j  [m89-verified]
#pragma unroll
  for (int fi = 0; fi < 2; fi++)
#pragma unroll
    for (int fj = 0; fj < FJ; fj++)
#pragma unroll
      for (int j = 0; j < 4; j++) {
        int mrow = wid * 32 + fi * 16 + (lane >> 4) * 4 + j;
        int col = fj * 16 + (lane & 15);
        Bs[mrow * CLD + col] = f2bf(acc[fi][fj][j]);
      }
  __syncthreads();
  const int CW = NOUT / 8;               // 16B chunks per row
  for (int task = tid; task < cnt * CW; task += 256) {
    int row = task / CW, c = task % CW;
    int slot = gf[ppos0 + row];          // sequential reads (row-major tasks)
    *(int4v*)&msgq[(size_t)slot * NOUT + c * 8] =
        *(const int4v*)&Bs[row * CLD + c * 8];
  }
}

// ---- phase 2: segmented reduce; msg rows CONTIGUOUS per node ----
template <int NOUT>
__global__ void k_reduce(const unsigned short* __restrict__ msg,
                         const int* __restrict__ nodeoff, int q0,
                         const float* __restrict__ bias, int do_relu,
                         unsigned short* __restrict__ outh,
                         float* __restrict__ outf) {
  int t = threadIdx.x;
  const int bpq = QN / 8;
  int qq = q0 + blockIdx.x / bpq;
  int rn = (blockIdx.x % bpq) * 8 + (t >> 5);
  if (rn >= QN) return;
  int n = qq * QN + rn;
  int l = t & 31;
  int lo = nodeoff[n + qq], hi = nodeoff[n + qq + 1];
  const unsigned short* m = msg + (size_t)(qq - q0) * MSGQ * NOUT;
  if (NOUT == 128) {
    float a0 = 0.f, a1 = 0.f, a2 = 0.f, a3 = 0.f;
    for (int i = lo; i < hi; i++) {
      uint2 v = *(const uint2*)&m[(size_t)i * 128 + l * 4];
      a0 += bf2f((unsigned short)(v.x & 0xffff));
      a1 += bf2f((unsigned short)(v.x >> 16));
      a2 += bf2f((unsigned short)(v.y & 0xffff));
      a3 += bf2f((unsigned short)(v.y >> 16));
    }
    a0 += bias[l * 4];     a1 += bias[l * 4 + 1];
    a2 += bias[l * 4 + 2]; a3 += bias[l * 4 + 3];
    if (do_relu) {
      a0 = fmaxf(a0, 0.f); a1 = fmaxf(a1, 0.f);
      a2 = fmaxf(a2, 0.f); a3 = fmaxf(a3, 0.f);
    }
    uint2 o;
    o.x = (unsigned)f2bf(a0) | ((unsigned)f2bf(a1) << 16);
    o.y = (unsigned)f2bf(a2) | ((unsigned)f2bf(a3) << 16);
    *(uint2*)&outh[(size_t)n * 128 + l * 4] = o;
  } else {
    float a0 = 0.f, a1 = 0.f;
    for (int i = lo; i < hi; i++) {
      unsigned v = *(const unsigned*)&m[(size_t)i * 64 + l * 2];
      a0 += bf2f((unsigned short)(v & 0xffff));
      a1 += bf2f((unsigned short)(v >> 16));
    }
    a0 += bias[l * 2];
    a1 += bias[l * 2 + 1];
    if (do_relu) { a0 = fmaxf(a0, 0.f); a1 = fmaxf(a1, 0.f); }
    outf[(size_t)n * 64 + l * 2]     = a0;
    outf[(size_t)n * 64 + l * 2 + 1] = a1;
  }
}

extern "C" void kernel_launch(void* const* d_in, const int* in_sizes, int n_in,
                              void* d_out, int out_size, void* d_ws, size_t ws_size,
                              hipStream_t stream) {
  const int* src = (const int*)d_in[0];
  const int* dst = (const int*)d_in[1];
  const int* et  = (const int*)d_in[2];
  const float* W0  = (const float*)d_in[3];
  const float* Wl0 = (const float*)d_in[4];
  const float* b0  = (const float*)d_in[5];
  const float* W1  = (const float*)d_in[6];
  const float* Wl1 = (const float*)d_in[7];
  const float* b1  = (const float*)d_in[8];
  const float* W2  = (const float*)d_in[9];
  const float* Wl2 = (const float*)d_in[10];
  const float* b2  = (const float*)d_in[11];

  char* ws = (char*)d_ws;
  size_t off = 0;
  auto alloc = [&](size_t bytes) {
    void* p = ws + off;
    off = (off + bytes + 255) & ~(size_t)255;
    return p;
  };
  unsigned short* msg = (unsigned short*)alloc((size_t)MSGQ * 128 * 2);  // 117.8 MB
  unsigned short* h1 = (unsigned short*)alloc((size_t)N_NODES * 128 * 2);
  unsigned short* h2 = (unsigned short*)alloc((size_t)N_NODES * 128 * 2);
  int* srcS = (int*)alloc((size_t)N_EDGES * 4);
  int* stgA = (int*)alloc((size_t)N_EDGES * 4);
  int* stgB = (int*)alloc((size_t)N_EDGES * 4);
  int* posE = (int*)alloc((size_t)N_EDGES * 4);
  int* gfwd = (int*)alloc((size_t)NQ * MSGQ * 4);   // 7.36 MB (pos -> slot)
  int* Rg   = (int*)alloc((size_t)N_RELS * N_NODES * 4);  // 7.6 MB
  int* ncount  = (int*)alloc((size_t)N_NODES * 4);
  int* nodeoff = (int*)alloc((size_t)(N_NODES + NQ + 4) * 4);
  int* histAll = (int*)alloc((size_t)S1B * NHC2 * 4);   // 2.92 MB [hK|hB|lK|lB]
  unsigned short* Wt1  = (unsigned short*)alloc((size_t)N_RELS * 128 * 128 * 2);
  unsigned short* Wt2  = (unsigned short*)alloc((size_t)N_RELS * 64 * 128 * 2);
  unsigned short* Wtl1 = (unsigned short*)alloc((size_t)128 * 128 * 2);
  unsigned short* Wtl2 = (unsigned short*)alloc((size_t)64 * 128 * 2);
  int* acc0 = (int*)alloc((size_t)(NBK8 + NBIN8) * 4);  // memset accumulators
  int* bcount8   = acc0;               // 608
  int* bincount8 = acc0 + NBK8;        // 3128
  int* ints = (int*)alloc(4096);       // non-memset bases
  int* boff   = ints;           // 77
  int* cbase  = ints + 80;      // 76
  int* qcs    = ints + 160;     // 5
  int* selfb  = ints + 168;     // 4
  int* bcur8  = (int*)alloc((size_t)NBK8 * 4);
  int* binoff8 = (int*)alloc((size_t)(NBIN8 + 1) * 4);
  int* bincur8 = (int*)alloc((size_t)NBIN8 * 4);
  int* bsum  = (int*)alloc((size_t)NSB * 4);
  int* bbase = (int*)alloc((size_t)NSB * 4);
  int* cA = (int*)alloc((size_t)NCK_TOT * 4);
  int* cB = (int*)alloc((size_t)NCK_TOT * 4);
  // total ~226 MB

  hipMemsetAsync(acc0, 0, (size_t)(NBK8 + NBIN8) * 4, stream);

  k_prep_w<<<1920, 256, 0, stream>>>(W1, W2, Wl1, Wl2, Wt1, Wt2, Wtl1, Wtl2);
  k_hist<<<S1B, 512, 0, stream>>>(dst, et, bcount8, bincount8, histAll);
  k_scan0<<<1, 512, 0, stream>>>(bcount8, bincount8, boff, bcur8, cbase, qcs,
                                 selfb, binoff8, bincur8);
  k_scat1a<<<S1B, 512, 0, stream>>>(src, dst, et, histAll, bcur8, srcS, posE);
  k_scat1b<<<S1B, 512, 0, stream>>>(src, dst, et, posE, histAll, bincur8,
                                    stgA, stgB);
  k_cnt<<<NBIN, 256, 0, stream>>>(stgB, binoff8, ncount);
  k_scanA<<<NSB, 256, 0, stream>>>(ncount, bsum);
  k_scanB<<<1, 512, 0, stream>>>(bsum, bbase, nodeoff);
  k_scanC<<<NSB, 256, 0, stream>>>(ncount, bbase, boff, nodeoff, gfwd);
  k_scat2<<<NBIN, 512, 0, stream>>>(stgA, stgB, binoff8, nodeoff, boff,
                                    ncount, gfwd, Rg);
  k_fill<<<N_BUCK + NQ, 256, 0, stream>>>(boff, cbase, selfb, cA, cB);
  k_h1<<<(N_NODES + 127) / 128, 256, 0, stream>>>(Rg, ncount, W0, Wl0, b0, h1);

  // ---- layer 1: per-quarter, 128 cols ----
  for (int q = 0; q < NQ; q++) {
    k_gemm_msg<128><<<NCKQ, 256, 0, stream>>>(h1, Wt1, Wtl1, qcs, q, 1, cA, cB,
                                              srcS, boff, gfwd, msg);
    k_reduce<128><<<QN / 8, 256, 0, stream>>>(msg, nodeoff, q, b1, 1,
                                              h2, nullptr);
  }
  // ---- layer 2: 2 quarters per pass, 64 cols (2 regions fit msg buffer) ----
  for (int qp = 0; qp < 2; qp++) {
    int q0 = 2 * qp;
    k_gemm_msg<64><<<2 * NCKQ, 256, 0, stream>>>(h2, Wt2, Wtl2, qcs, q0, 2,
                                                 cA, cB, srcS, boff, gfwd, msg);
    k_reduce<64><<<2 * (QN / 8), 256, 0, stream>>>(msg, nodeoff, q0, b2, 0,
                                                   nullptr, (float*)d_out);
  }
}

// Round 18
// 610.115 us; speedup vs baseline: 1.0271x; 1.0271x over previous
//
#include <hip/hip_runtime.h>
#include <hip/hip_bf16.h>
#include <stdint.h>

#define N_NODES 100000
#define N_EDGES 1600000
#define N_RELS  19
#define NQ      4                   // dst quarters
#define QN      25000               // nodes per quarter
#define QTILES  196                 // ceil(QN/128)
#define NBQ     98                  // scan blocks per quarter (256 nodes each)
#define NSB     (NQ * NBQ)          // 392
#define N_BUCK  (NQ * N_RELS)       // 76
#define NBIN    391                 // dst bins of 256 nodes
#define NGR     8                   // counter groups (~XCDs); blk%8 -> same XCD
#define NBK8    (N_BUCK * NGR)      // 608
#define NBIN8   (NBIN * NGR)       // 3128
#define NHC     (N_BUCK + NBIN)     // 467 hist counters per block
#define NHC2    (2 * NHC)           // 934: [hK|hB|lK|lB]
#define MSGQ    460000              // msg rows per quarter (edges + QN + margin)
#define NCKQ    3700                // gemm grid per quarter pass
#define NCK_TOT 14000
#define EPB     2048                // edges per S1 block
#define S1B     782                 // ceil(N_EDGES/EPB)

typedef __attribute__((ext_vector_type(8))) short bf16x8;
typedef __attribute__((ext_vector_type(4))) float f32x4;
typedef __attribute__((ext_vector_type(4))) int   int4v;

__device__ __forceinline__ unsigned short f2bf(float x) {
  union { float f; unsigned u; } v; v.f = x;
  unsigned r = v.u + 0x7FFF + ((v.u >> 16) & 1);
  return (unsigned short)(r >> 16);
}
__device__ __forceinline__ float bf2f(unsigned short b) {
  union { unsigned u; float f; } v; v.u = ((unsigned)b) << 16; return v.f;
}

// ---------------- weight prep: transpose + bf16 convert ----------------
__global__ void k_prep_w(const float* W1, const float* W2,
                         const float* Wl1, const float* Wl2,
                         unsigned short* Wt1, unsigned short* Wt2,
                         unsigned short* Wtl1, unsigned short* Wtl2) {
  int i = blockIdx.x * 256 + threadIdx.x;
  const int s1 = N_RELS * 128 * 128;
  const int s2 = N_RELS * 64 * 128;
  const int s3 = 128 * 128;
  const int s4 = 64 * 128;
  if (i < s1) {
    int r = i / (128 * 128); int rem = i % (128 * 128);
    int n = rem / 128, k = rem % 128;
    Wt1[i] = f2bf(W1[((size_t)r * 128 + k) * 128 + n]);
  } else if (i < s1 + s2) {
    int j = i - s1;
    int r = j / (64 * 128); int rem = j % (64 * 128);
    int n = rem / 128, k = rem % 128;
    Wt2[j] = f2bf(W2[((size_t)r * 128 + k) * 64 + n]);
  } else if (i < s1 + s2 + s3) {
    int j = i - s1 - s2; int n = j / 128, k = j % 128;
    Wtl1[j] = f2bf(Wl1[k * 128 + n]);
  } else if (i < s1 + s2 + s3 + s4) {
    int j = i - s1 - s2 - s3; int n = j / 128, k = j % 128;
    Wtl2[j] = f2bf(Wl2[k * 64 + n]);
  }
}

// ---- histogram + local exclusive scans; persists [hK|hB|lK|lB] ----
// 512 threads: halves histogram atomic chains; scans guarded to t<256
__launch_bounds__(512)
__global__ void k_hist(const int* __restrict__ dst, const int* __restrict__ et,
                       int* __restrict__ bcount8, int* __restrict__ bincount8,
                       int* __restrict__ histAll) {
  __shared__ int hK[N_BUCK], hB[NBIN];
  __shared__ int sb[256];
  int t = threadIdx.x, g = blockIdx.x & (NGR - 1);
  for (int i = t; i < N_BUCK; i += 512) hK[i] = 0;
  for (int i = t; i < NBIN; i += 512) hB[i] = 0;
  __syncthreads();
  int e0 = blockIdx.x * EPB;
  for (int r = 0; r < EPB / 512; r++) {
    int e = e0 + r * 512 + t;
    if (e < N_EDGES) {
      int d = dst[e];
      atomicAdd(&hK[(d / QN) * N_RELS + et[e]], 1);
      atomicAdd(&hB[d >> 8], 1);
    }
  }
  __syncthreads();
  int* hout = histAll + (size_t)blockIdx.x * NHC2;
  for (int i = t; i < N_BUCK; i += 512) {
    hout[i] = hK[i];
    if (hK[i]) atomicAdd(&bcount8[i * NGR + g], hK[i]);
  }
  for (int i = t; i < NBIN; i += 512) {
    hout[N_BUCK + i] = hB[i];
    if (hB[i]) atomicAdd(&bincount8[i * NGR + g], hB[i]);
  }
  // local exclusive scan hK -> lK  (threads 0..255)
  {
    int v0 = 0, v1 = 0;
    if (t < 256) {
      v0 = (2 * t < N_BUCK) ? hK[2 * t] : 0;
      v1 = (2 * t + 1 < N_BUCK) ? hK[2 * t + 1] : 0;
      sb[t] = v0 + v1;
    }
    __syncthreads();
    for (int s = 1; s < 256; s <<= 1) {
      int x = 0;
      if (t < 256 && t >= s) x = sb[t - s];
      __syncthreads();
      if (t < 256) sb[t] += x;
      __syncthreads();
    }
    if (t < 256) {
      int base = sb[t] - v0 - v1;
      if (2 * t < N_BUCK) hout[NHC + 2 * t] = base;
      if (2 * t + 1 < N_BUCK) hout[NHC + 2 * t + 1] = base + v0;
    }
    __syncthreads();
  }
  // local exclusive scan hB -> lB  (threads 0..255)
  {
    int v0 = 0, v1 = 0;
    if (t < 256) {
      v0 = (2 * t < NBIN) ? hB[2 * t] : 0;
      v1 = (2 * t + 1 < NBIN) ? hB[2 * t + 1] : 0;
      sb[t] = v0 + v1;
    }
    __syncthreads();
    for (int s = 1; s < 256; s <<= 1) {
      int x = 0;
      if (t < 256 && t >= s) x = sb[t - s];
      __syncthreads();
      if (t < 256) sb[t] += x;
      __syncthreads();
    }
    if (t < 256) {
      int base = sb[t] - v0 - v1;
      if (2 * t < NBIN) hout[NHC + N_BUCK + 2 * t] = base;
      if (2 * t + 1 < NBIN) hout[NHC + N_BUCK + 2 * t + 1] = base + v0;
    }
  }
}

// ---- scan0: bucket/chunk bases + (bucket,group)/(bin,group) prefix ----
__global__ void k_scan0(const int* __restrict__ bcount8, const int* __restrict__ bincount8,
                        int* boff, int* bcur8, int* cbase, int* qcs, int* selfb,
                        int* binoff8, int* bincur8) {
  __shared__ int shK[NBK8];
  __shared__ int sb76[N_BUCK];
  __shared__ int sbs[N_BUCK];
  __shared__ int sh[512];
  int t = threadIdx.x;   // 512
  for (int i = t; i < NBK8; i += 512) shK[i] = bcount8[i];
  __syncthreads();
  if (t < N_BUCK) {
    int s = 0;
    for (int gg = 0; gg < NGR; gg++) s += shK[t * NGR + gg];
    sb76[t] = s;
  }
  __syncthreads();
  if (t == 0) {
    int a = 0, cb = 0;
    for (int q = 0; q < NQ; q++) {
      qcs[q] = cb;
      for (int r = 0; r < N_RELS; r++) {
        int b = q * N_RELS + r;
        boff[b] = a; sbs[b] = a; cbase[b] = cb;
        a += sb76[b]; cb += (sb76[b] + 127) >> 7;
      }
      selfb[q] = cb; cb += QTILES;
    }
    qcs[NQ] = cb;
    boff[N_BUCK] = a;
  }
  __syncthreads();
  for (int i = t; i < NBK8; i += 512) {
    int b = i >> 3, gg = i & (NGR - 1);
    int base = sbs[b];
    for (int k = 0; k < gg; k++) base += shK[b * NGR + k];
    bcur8[i] = base;
  }
  // ---- bin part: exclusive scan of 3128 per-(bin,group) counts ----
  int vals[7];
  int i0 = t * 7;
  int loc = 0;
  for (int k = 0; k < 7; k++) {
    int i = i0 + k;
    int v = (i < NBIN8) ? bincount8[i] : 0;
    vals[k] = v; loc += v;
  }
  sh[t] = loc;
  __syncthreads();
  for (int s = 1; s < 512; s <<= 1) {
    int x = (t >= s) ? sh[t - s] : 0;
    __syncthreads();
    sh[t] += x;
    __syncthreads();
  }
  int run = sh[t] - loc;
  for (int k = 0; k < 7; k++) {
    int i = i0 + k;
    if (i < NBIN8) { binoff8[i] = run; bincur8[i] = run; run += vals[k]; }
  }
  if (t == 511) binoff8[NBIN8] = sh[511];   // total
}

// ---- S1a: bucket counting-sort -> srcS (coalesced runs) + posE (seq) ----
__launch_bounds__(512)
__global__ void k_scat1a(const int* __restrict__ src, const int* __restrict__ dst,
                         const int* __restrict__ et,
                         const int* __restrict__ histAll,
                         int* __restrict__ bcur8,
                         int* __restrict__ srcS, int* __restrict__ posE) {
  __shared__ int sortK[EPB];
  __shared__ int lK[N_BUCK], gKr[N_BUCK];
  int t = threadIdx.x, blk = blockIdx.x, g = blk & (NGR - 1);
  const int* hin = histAll + (size_t)blk * NHC2;
  for (int i = t; i < N_BUCK; i += 512) {
    int h = hin[i], l = hin[NHC + i];
    lK[i] = l;
    gKr[i] = h ? (atomicAdd(&bcur8[i * NGR + g], h) - l) : 0;
  }
  __syncthreads();
  int e0 = blk * EPB;
  int nval = min(EPB, N_EDGES - e0);
  for (int r = 0; r < EPB / 512; r++) {
    int e = e0 + r * 512 + t;
    if (e < N_EDGES) {
      int d = dst[e], rl = et[e], sv = src[e];
      int bk = (d / QN) * N_RELS + rl;
      int lrk = atomicAdd(&lK[bk], 1);
      sortK[lrk] = sv | (bk << 17);
      posE[e] = gKr[bk] + lrk;      // global bucket position, seq write in e
    }
  }
  __syncthreads();
  for (int r = 0; r < EPB / 512; r++) {
    int s = r * 512 + t;
    if (s < nval) {
      int v = sortK[s];
      srcS[gKr[v >> 17] + s] = v & 0x1FFFF;
    }
  }
}

// ---- S1b: bin counting-sort -> stgA/stgB (coalesced runs), 512 threads ----
__launch_bounds__(512)
__global__ void k_scat1b(const int* __restrict__ src, const int* __restrict__ dst,
                         const int* __restrict__ et,
                         const int* __restrict__ posE,
                         const int* __restrict__ histAll,
                         int* __restrict__ bincur8,
                         int* __restrict__ stgA, int* __restrict__ stgB) {
  __shared__ int sortA[EPB], sortBv[EPB];
  __shared__ int lB[NBIN], gBr[NBIN];
  int t = threadIdx.x, blk = blockIdx.x, g = blk & (NGR - 1);
  const int* hin = histAll + (size_t)blk * NHC2;
  for (int i = t; i < NBIN; i += 512) {
    int h = hin[N_BUCK + i], l = hin[NHC + N_BUCK + i];
    lB[i] = l;
    gBr[i] = h ? (atomicAdd(&bincur8[i * NGR + g], h) - l) : 0;
  }
  __syncthreads();
  int e0 = blk * EPB;
  int nval = min(EPB, N_EDGES - e0);
  for (int r = 0; r < EPB / 512; r++) {
    int e = e0 + r * 512 + t;
    if (e < N_EDGES) {
      int d = dst[e], rl = et[e], sv = src[e];
      int gpos = posE[e];
      int bn = d >> 8;
      int lrb = atomicAdd(&lB[bn], 1);
      sortA[lrb] = gpos | (rl << 21) | ((bn & 63) << 26);
      sortBv[lrb] = sv | ((d & 255) << 17) | ((bn >> 6) << 25);
    }
  }
  __syncthreads();
  for (int r = 0; r < EPB / 512; r++) {
    int s = r * 512 + t;
    if (s < nval) {
      int a = sortA[s], b = sortBv[s];
      int bn = ((a >> 26) & 63) | (((b >> 25) & 7) << 6);
      int adr = gBr[bn] + s;
      stgA[adr] = a & 0x03FFFFFF;
      stgB[adr] = b & 0x01FFFFFF;
    }
  }
}

// ---- S2a: per-bin indegree counts (single-writer, no global atomics) ----
__global__ void k_cnt(const int* __restrict__ stgB, const int* __restrict__ binoff8,
                      int* __restrict__ ncount) {
  __shared__ int c[256];
  int b = blockIdx.x, t = threadIdx.x;
  c[t] = 0;
  __syncthreads();
  int lo = binoff8[b * NGR], hi = binoff8[b * NGR + NGR];
  for (int s = lo + t; s < hi; s += 256)
    atomicAdd(&c[(stgB[s] >> 17) & 255], 1);
  __syncthreads();
  int n = b * 256 + t;
  if (n < N_NODES) ncount[n] = c[t];
}

// ---- scan stage A: per-256-node block sums of (ncount+1) ----
__global__ void k_scanA(const int* __restrict__ ncount, int* __restrict__ bsum) {
  __shared__ int sh[256];
  int b = blockIdx.x, t = threadIdx.x;
  int q = b / NBQ, bb = b % NBQ;
  int i = bb * 256 + t;
  int val = (i < QN) ? (ncount[q * QN + i] + 1) : 0;
  sh[t] = val;
  __syncthreads();
  for (int s = 128; s > 0; s >>= 1) {
    if (t < s) sh[t] += sh[t + s];
    __syncthreads();
  }
  if (t == 0) bsum[b] = sh[0];
}

// ---- scan stage B: per-quarter prefix over block sums + sentinels ----
__global__ void k_scanB(const int* bsum, int* bbase, int* nodeoff) {
  __shared__ int sh[NSB];
  int t = threadIdx.x;   // 512
  if (t < NSB) sh[t] = bsum[t];
  __syncthreads();
  if (t < NQ) {
    int a = 0;
    for (int i = 0; i < NBQ; i++) {
      int v = sh[t * NBQ + i]; sh[t * NBQ + i] = a; a += v;
    }
    nodeoff[(t + 1) * QN + t] = a;      // quarter sentinel
  }
  __syncthreads();
  if (t < NSB) bbase[t] = sh[t];
}

// ---- scan stage C: intra-block scan -> nodeoff; also gfwd self slots ----
__global__ void k_scanC(const int* __restrict__ ncount,
                        const int* __restrict__ bbase,
                        const int* __restrict__ boff,
                        int* __restrict__ nodeoff, int* __restrict__ gfwd) {
  __shared__ int sh[256];
  int b = blockIdx.x, t = threadIdx.x;
  int q = b / NBQ, bb = b % NBQ;
  int i = bb * 256 + t;
  int val = (i < QN) ? (ncount[q * QN + i] + 1) : 0;
  sh[t] = val;
  __syncthreads();
  for (int s = 1; s < 256; s <<= 1) {
    int x = (t >= s) ? sh[t - s] : 0;
    __syncthreads();
    sh[t] += x;
    __syncthreads();
  }
  int excl = sh[t] - val + bbase[b];
  if (i < QN) {
    int n = q * QN + i;
    nodeoff[n + q] = excl;                 // slot 0 of run = self message
    int qedges = boff[(q + 1) * N_RELS] - boff[q * N_RELS];
    gfwd[(size_t)q * MSGQ + qedges + i] = excl;   // self pos -> slot
  }
}

// ---- S2b: slot assignment -> gfwd[pos]=slot + fused R accumulation ----
__launch_bounds__(512)
__global__ void k_scat2(const int* __restrict__ stgA, const int* __restrict__ stgB,
                        const int* __restrict__ binoff8,
                        const int* __restrict__ nodeoff,
                        const int* __restrict__ boff,
                        const int* __restrict__ ncount,
                        int* __restrict__ gfwd, int* __restrict__ Rg) {
  __shared__ int cur[256];
  __shared__ int R[256][N_RELS];
  __shared__ int qe0s[NQ + 1];
  int b = blockIdx.x, t = threadIdx.x;
  if (t <= NQ) qe0s[t] = boff[t * N_RELS];
  if (t < 256) {
    int n = b * 256 + t;
    if (n < N_NODES) {
      int q = n / QN;
      cur[t] = nodeoff[n + q] + 1;
    }
#pragma unroll
    for (int r = 0; r < N_RELS; r++) R[t][r] = 0;
  }
  __syncthreads();
  int lo = binoff8[b * NGR], hi = binoff8[b * NGR + NGR];
  for (int s = lo + t; s < hi; s += 512) {
    int a = stgA[s], bb = stgB[s];
    int dlow = (bb >> 17) & 255;
    int slot = atomicAdd(&cur[dlow], 1);
    int pos = a & 0x1FFFFF, rel = (a >> 21) & 31;
    int sv = bb & 0x1FFFF;
    int d = b * 256 + dlow;
    int q = d / QN;
    gfwd[(size_t)q * MSGQ + (pos - qe0s[q])] = slot;
    atomicAdd(&R[dlow][rel], ncount[sv]);
  }
  __syncthreads();
  if (t < 256) {
    int n = b * 256 + t;
    if (n < N_NODES) {
#pragma unroll
      for (int r = 0; r < N_RELS; r++)
        Rg[(size_t)r * N_NODES + n] = R[t][r];
    }
  }
}

// ---- layer 0 dense: h1 = relu([R|deg]·W0ext + b0), LDS-staged linear write ----
__launch_bounds__(256, 3)
__global__ void k_h1(const int* __restrict__ Rg, const int* __restrict__ ncount,
                     const float* __restrict__ W0, const float* __restrict__ Wl0,
                     const float* __restrict__ b0,
                     unsigned short* __restrict__ h1) {
  __shared__ float W0s[N_RELS * 128];
  __shared__ float wl[128], bb[128];
  __shared__ __align__(16) unsigned short Hs[128 * 128];
  int t = threadIdx.x, blk = blockIdx.x;
  for (int i = t; i < N_RELS * 128; i += 256) W0s[i] = W0[i];
  if (t < 128) { wl[t] = Wl0[t]; bb[t] = b0[t]; }
  __syncthreads();
  int n0 = blk * 128;
  int cnt = min(128, N_NODES - n0);
  int ln = t >> 1;                 // local node (2 threads per node)
  int half = (t & 1) * 64;         // this thread's 64-col half
  if (ln < cnt) {
    int n = n0 + ln;
    float rr[N_RELS];
#pragma unroll
    for (int r = 0; r < N_RELS; r++) rr[r] = (float)Rg[(size_t)r * N_NODES + n];
    float dn = (float)ncount[n];
    for (int c0 = half; c0 < half + 64; c0 += 8) {
      float acc[8];
#pragma unroll
      for (int j = 0; j < 8; j++) acc[j] = dn * wl[c0 + j] + bb[c0 + j];
      for (int r = 0; r < N_RELS; r++) {
#pragma unroll
        for (int j = 0; j < 8; j++)
          acc[j] += rr[r] * W0s[r * 128 + c0 + j];
      }
      unsigned vs[4];
#pragma unroll
      for (int j = 0; j < 4; j++) {
        float x0 = fmaxf(acc[2 * j], 0.f), x1 = fmaxf(acc[2 * j + 1], 0.f);
        vs[j] = (unsigned)f2bf(x0) | ((unsigned)f2bf(x1) << 16);
      }
      int4v o = {(int)vs[0], (int)vs[1], (int)vs[2], (int)vs[3]};
      *(int4v*)&Hs[ln * 128 + c0] = o;
    }
  }
  __syncthreads();
  int tot = cnt * 16;              // 16 x 16B chunks per node row
  for (int task = t; task < tot; task += 256)
    *(int4v*)&h1[(size_t)n0 * 128 + task * 8] = *(const int4v*)&Hs[task * 8];
}

// ---- chunk list: edge chunks per bucket + self chunks per quarter ----
__global__ void k_fill(const int* boff, const int* cbase,
                       const int* selfb, int* cA, int* cB) {
  int b = blockIdx.x;
  if (b < N_BUCK) {
    int cnt = boff[b + 1] - boff[b], e0 = boff[b], w0 = cbase[b];
    int rel = b % N_RELS;
    int nch = (cnt + 127) >> 7;
    for (int i = threadIdx.x; i < nch; i += blockDim.x) {
      cA[w0 + i] = (e0 + i * 128) | (rel << 21);
      cB[w0 + i] = min(128, cnt - i * 128);
    }
  } else {
    int q = b - N_BUCK;
    int w0 = selfb[q];
    for (int i = threadIdx.x; i < QTILES; i += blockDim.x) {
      cA[w0 + i] = (i * 128) | (19 << 21);
      cB[w0 + i] = min(128, QN - i * 128);
    }
  }
}

// ---- phase 1: GEMM -> msg rows scattered to DST-SORTED slots via gfwd ----
// nqp quarters per launch (layer2 packs 2 quarters into the msg buffer)
template <int NOUT>
__launch_bounds__(256, NOUT == 64 ? 6 : 4)
__global__ void k_gemm_msg(const unsigned short* __restrict__ hprev,  // bf16 N x 128
                           const unsigned short* __restrict__ Wt,    // [19][NOUT][128]
                           const unsigned short* __restrict__ Wtl,   // [NOUT][128]
                           const int* __restrict__ qcs, int q0, int nqp,
                           const int* __restrict__ cA,
                           const int* __restrict__ cB,
                           const int* __restrict__ srcS,
                           const int* __restrict__ boff,
                           const int* __restrict__ gfwd,   // full (quarter-major)
                           unsigned short* __restrict__ msg) {
  const int LDK = 136;                    // B stride (shorts)
  const int CLD = NOUT + 8;               // C stride (shorts)
  const int SH = (NOUT * LDK > 128 * CLD) ? NOUT * LDK : 128 * CLD;
  __shared__ __align__(16) unsigned short Bs[SH];

  int cs = qcs[q0], ce = qcs[q0 + nqp];
  int w = blockIdx.x;
  if (w >= ce - cs) return;
  w += cs;
  int qq = q0;
  if (nqp == 2 && w >= qcs[q0 + 1]) qq = q0 + 1;
  int pa = cA[w];
  int e0 = pa & 0x1FFFFF, rel = pa >> 21;
  int cnt = cB[w];
  bool self = (rel == 19);
  const unsigned short* wsrc = self ? Wtl : (Wt + (size_t)rel * NOUT * 128);
  int qe0 = boff[qq * N_RELS];
  int qedges = boff[(qq + 1) * N_RELS] - qe0;
  int ppos0 = self ? (qedges + e0) : (e0 - qe0);
  const int* gf = gfwd + (size_t)qq * MSGQ;
  unsigned short* msgq = msg + (size_t)(qq - q0) * MSGQ * NOUT;
  int tid = threadIdx.x;
  const int lane = tid & 63, wid = tid >> 6;

  int rowg[2]; bool valv[2];
#pragma unroll
  for (int fi = 0; fi < 2; fi++) {
    int m = wid * 32 + fi * 16 + (lane & 15);
    bool v = m < cnt;
    valv[fi] = v;
    int row = 0;
    if (v) row = self ? (qq * QN + e0 + m) : srcS[e0 + m];
    rowg[fi] = row;
  }
  bf16x8 a[2][4];
#pragma unroll
  for (int fi = 0; fi < 2; fi++) {
    const unsigned short* rp = hprev + (size_t)rowg[fi] * 128 + (lane >> 4) * 8;
#pragma unroll
    for (int kk = 0; kk < 4; kk++)
      a[fi][kk] = *(const bf16x8*)&rp[kk * 32];
  }
#pragma unroll
  for (int fi = 0; fi < 2; fi++)
    if (!valv[fi]) {
#pragma unroll
      for (int kk = 0; kk < 4; kk++)
        a[fi][kk] = (bf16x8){0, 0, 0, 0, 0, 0, 0, 0};
    }

  for (int task = tid; task < NOUT * 16; task += 256) {
    int n = task >> 4, c = task & 15;
    *(int4v*)&Bs[n * LDK + c * 8] = *(const int4v*)&wsrc[n * 128 + c * 8];
  }
  __syncthreads();

  const int FJ = NOUT / 16;
  f32x4 acc[2][FJ];
#pragma unroll
  for (int i = 0; i < 2; i++)
#pragma unroll
    for (int j = 0; j < FJ; j++) acc[i][j] = (f32x4){0.f, 0.f, 0.f, 0.f};

#pragma unroll
  for (int kk = 0; kk < 4; kk++) {
    int kof = kk * 32 + (lane >> 4) * 8;
    bf16x8 b[FJ];
#pragma unroll
    for (int fj = 0; fj < FJ; fj++)
      b[fj] = *(const bf16x8*)&Bs[(fj * 16 + (lane & 15)) * LDK + kof];
#pragma unroll
    for (int fi = 0; fi < 2; fi++)
#pragma unroll
      for (int fj = 0; fj < FJ; fj++)
        acc[fi][fj] = __builtin_amdgcn_mfma_f32_16x16x32_bf16(a[fi][kk], b[fj], acc[fi][fj], 0, 0, 0);
  }

  // ---- epilogue: C -> LDS (stride CLD) -> scattered full-row 16B stores ----
  __syncthreads();                       // all waves done reading Bs
  // C/D: col=lane&15, row=(lane>>4)*4+j  [m89-verified]
#pragma unroll
  for (int fi = 0; fi < 2; fi++)
#pragma unroll
    for (int fj = 0; fj < FJ; fj++)
#pragma unroll
      for (int j = 0; j < 4; j++) {
        int mrow = wid * 32 + fi * 16 + (lane >> 4) * 4 + j;
        int col = fj * 16 + (lane & 15);
        Bs[mrow * CLD + col] = f2bf(acc[fi][fj][j]);
      }
  __syncthreads();
  const int CW = NOUT / 8;               // 16B chunks per row
  for (int task = tid; task < cnt * CW; task += 256) {
    int row = task / CW, c = task % CW;
    int slot = gf[ppos0 + row];          // sequential reads (row-major tasks)
    *(int4v*)&msgq[(size_t)slot * NOUT + c * 8] =
        *(const int4v*)&Bs[row * CLD + c * 8];
  }
}

// ---- phase 2: segmented reduce; msg rows CONTIGUOUS per node ----
template <int NOUT>
__global__ void k_reduce(const unsigned short* __restrict__ msg,
                         const int* __restrict__ nodeoff, int q0,
                         const float* __restrict__ bias, int do_relu,
                         unsigned short* __restrict__ outh,
                         float* __restrict__ outf) {
  int t = threadIdx.x;
  const int bpq = QN / 8;
  int qq = q0 + blockIdx.x / bpq;
  int rn = (blockIdx.x % bpq) * 8 + (t >> 5);
  if (rn >= QN) return;
  int n = qq * QN + rn;
  int l = t & 31;
  int lo = nodeoff[n + qq], hi = nodeoff[n + qq + 1];
  const unsigned short* m = msg + (size_t)(qq - q0) * MSGQ * NOUT;
  if (NOUT == 128) {
    float a0 = 0.f, a1 = 0.f, a2 = 0.f, a3 = 0.f;
    for (int i = lo; i < hi; i++) {
      uint2 v = *(const uint2*)&m[(size_t)i * 128 + l * 4];
      a0 += bf2f((unsigned short)(v.x & 0xffff));
      a1 += bf2f((unsigned short)(v.x >> 16));
      a2 += bf2f((unsigned short)(v.y & 0xffff));
      a3 += bf2f((unsigned short)(v.y >> 16));
    }
    a0 += bias[l * 4];     a1 += bias[l * 4 + 1];
    a2 += bias[l * 4 + 2]; a3 += bias[l * 4 + 3];
    if (do_relu) {
      a0 = fmaxf(a0, 0.f); a1 = fmaxf(a1, 0.f);
      a2 = fmaxf(a2, 0.f); a3 = fmaxf(a3, 0.f);
    }
    uint2 o;
    o.x = (unsigned)f2bf(a0) | ((unsigned)f2bf(a1) << 16);
    o.y = (unsigned)f2bf(a2) | ((unsigned)f2bf(a3) << 16);
    *(uint2*)&outh[(size_t)n * 128 + l * 4] = o;
  } else {
    float a0 = 0.f, a1 = 0.f;
    for (int i = lo; i < hi; i++) {
      unsigned v = *(const unsigned*)&m[(size_t)i * 64 + l * 2];
      a0 += bf2f((unsigned short)(v & 0xffff));
      a1 += bf2f((unsigned short)(v >> 16));
    }
    a0 += bias[l * 2];
    a1 += bias[l * 2 + 1];
    if (do_relu) { a0 = fmaxf(a0, 0.f); a1 = fmaxf(a1, 0.f); }
    outf[(size_t)n * 64 + l * 2]     = a0;
    outf[(size_t)n * 64 + l * 2 + 1] = a1;
  }
}

extern "C" void kernel_launch(void* const* d_in, const int* in_sizes, int n_in,
                              void* d_out, int out_size, void* d_ws, size_t ws_size,
                              hipStream_t stream) {
  const int* src = (const int*)d_in[0];
  const int* dst = (const int*)d_in[1];
  const int* et  = (const int*)d_in[2];
  const float* W0  = (const float*)d_in[3];
  const float* Wl0 = (const float*)d_in[4];
  const float* b0  = (const float*)d_in[5];
  const float* W1  = (const float*)d_in[6];
  const float* Wl1 = (const float*)d_in[7];
  const float* b1  = (const float*)d_in[8];
  const float* W2  = (const float*)d_in[9];
  const float* Wl2 = (const float*)d_in[10];
  const float* b2  = (const float*)d_in[11];

  char* ws = (char*)d_ws;
  size_t off = 0;
  auto alloc = [&](size_t bytes) {
    void* p = ws + off;
    off = (off + bytes + 255) & ~(size_t)255;
    return p;
  };
  unsigned short* msg = (unsigned short*)alloc((size_t)MSGQ * 128 * 2);  // 117.8 MB
  unsigned short* h1 = (unsigned short*)alloc((size_t)N_NODES * 128 * 2);
  unsigned short* h2 = (unsigned short*)alloc((size_t)N_NODES * 128 * 2);
  int* srcS = (int*)alloc((size_t)N_EDGES * 4);
  int* stgA = (int*)alloc((size_t)N_EDGES * 4);
  int* stgB = (int*)alloc((size_t)N_EDGES * 4);
  int* posE = (int*)alloc((size_t)N_EDGES * 4);
  int* gfwd = (int*)alloc((size_t)NQ * MSGQ * 4);   // 7.36 MB (pos -> slot)
  int* Rg   = (int*)alloc((size_t)N_RELS * N_NODES * 4);  // 7.6 MB
  int* ncount  = (int*)alloc((size_t)N_NODES * 4);
  int* nodeoff = (int*)alloc((size_t)(N_NODES + NQ + 4) * 4);
  int* histAll = (int*)alloc((size_t)S1B * NHC2 * 4);   // 2.92 MB [hK|hB|lK|lB]
  unsigned short* Wt1  = (unsigned short*)alloc((size_t)N_RELS * 128 * 128 * 2);
  unsigned short* Wt2  = (unsigned short*)alloc((size_t)N_RELS * 64 * 128 * 2);
  unsigned short* Wtl1 = (unsigned short*)alloc((size_t)128 * 128 * 2);
  unsigned short* Wtl2 = (unsigned short*)alloc((size_t)64 * 128 * 2);
  int* acc0 = (int*)alloc((size_t)(NBK8 + NBIN8) * 4);  // memset accumulators
  int* bcount8   = acc0;               // 608
  int* bincount8 = acc0 + NBK8;        // 3128
  int* ints = (int*)alloc(4096);       // non-memset bases
  int* boff   = ints;           // 77
  int* cbase  = ints + 80;      // 76
  int* qcs    = ints + 160;     // 5
  int* selfb  = ints + 168;     // 4
  int* bcur8  = (int*)alloc((size_t)NBK8 * 4);
  int* binoff8 = (int*)alloc((size_t)(NBIN8 + 1) * 4);
  int* bincur8 = (int*)alloc((size_t)NBIN8 * 4);
  int* bsum  = (int*)alloc((size_t)NSB * 4);
  int* bbase = (int*)alloc((size_t)NSB * 4);
  int* cA = (int*)alloc((size_t)NCK_TOT * 4);
  int* cB = (int*)alloc((size_t)NCK_TOT * 4);
  // total ~226 MB

  hipMemsetAsync(acc0, 0, (size_t)(NBK8 + NBIN8) * 4, stream);

  k_prep_w<<<1920, 256, 0, stream>>>(W1, W2, Wl1, Wl2, Wt1, Wt2, Wtl1, Wtl2);
  k_hist<<<S1B, 512, 0, stream>>>(dst, et, bcount8, bincount8, histAll);
  k_scan0<<<1, 512, 0, stream>>>(bcount8, bincount8, boff, bcur8, cbase, qcs,
                                 selfb, binoff8, bincur8);
  k_scat1a<<<S1B, 512, 0, stream>>>(src, dst, et, histAll, bcur8, srcS, posE);
  k_scat1b<<<S1B, 512, 0, stream>>>(src, dst, et, posE, histAll, bincur8,
                                    stgA, stgB);
  k_cnt<<<NBIN, 256, 0, stream>>>(stgB, binoff8, ncount);
  k_scanA<<<NSB, 256, 0, stream>>>(ncount, bsum);
  k_scanB<<<1, 512, 0, stream>>>(bsum, bbase, nodeoff);
  k_scanC<<<NSB, 256, 0, stream>>>(ncount, bbase, boff, nodeoff, gfwd);
  k_scat2<<<NBIN, 512, 0, stream>>>(stgA, stgB, binoff8, nodeoff, boff,
                                    ncount, gfwd, Rg);
  k_fill<<<N_BUCK + NQ, 256, 0, stream>>>(boff, cbase, selfb, cA, cB);
  k_h1<<<(N_NODES + 127) / 128, 256, 0, stream>>>(Rg, ncount, W0, Wl0, b0, h1);

  // ---- layer 1: per-quarter, 128 cols ----
  for (int q = 0; q < NQ; q++) {
    k_gemm_msg<128><<<NCKQ, 256, 0, stream>>>(h1, Wt1, Wtl1, qcs, q, 1, cA, cB,
                                              srcS, boff, gfwd, msg);
    k_reduce<128><<<QN / 8, 256, 0, stream>>>(msg, nodeoff, q, b1, 1,
                                              h2, nullptr);
  }
  // ---- layer 2: 2 quarters per pass, 64 cols (2 regions fit msg buffer) ----
  for (int qp = 0; qp < 2; qp++) {
    int q0 = 2 * qp;
    k_gemm_msg<64><<<2 * NCKQ, 256, 0, stream>>>(h2, Wt2, Wtl2, qcs, q0, 2,
                                                 cA, cB, srcS, boff, gfwd, msg);
    k_reduce<64><<<2 * (QN / 8), 256, 0, stream>>>(msg, nodeoff, q0, b2, 0,
                                                   nullptr, (float*)d_out);
  }
}